// Round 1
// baseline (800.129 us; speedup 1.0000x reference)
//
#include <hip/hip_runtime.h>
#include <math.h>

#define BATCH 16
#define SEQ 512
#define HID 768
#define NHEAD 4
#define HDIM 192
#define NLBL 9
#define ROWS (BATCH*SEQ)                 // 8192
#define INV_SQRT_D 0.07216878364870323f  // 1/sqrt(192)

// ---------------------------------------------------------------------------
// 128x128x8 fp32 GEMM body: C = A[M,K] @ W[K,N] + bias[N] (+ Res[M,N])
// 256 threads, 8x8 micro-tile as 2x2 quadrants (rows {tr,tr+64}, cols {tc,tc+64})
// so all LDS fragment reads are aligned b128 with <=2-way bank aliasing (free).
// ---------------------------------------------------------------------------
__device__ __forceinline__ void gemm128_body(
    const float* __restrict__ A, const float* __restrict__ W,
    const float* __restrict__ bias, const float* __restrict__ Res,
    float* __restrict__ C, const int M, const int N, const int K)
{
  __shared__ float As[8][132];
  __shared__ float Bs[8][132];
  const int tid = threadIdx.x;
  const int bm = blockIdx.y * 128;
  const int bn = blockIdx.x * 128;
  const int tr = (tid >> 4) * 4;      // 0..60
  const int tc = (tid & 15) * 4;      // 0..60
  const int am  = tid >> 1;           // 0..127
  const int ak  = (tid & 1) * 4;      // 0,4
  const int bkr = tid >> 5;           // 0..7
  const int bn4 = (tid & 31) * 4;     // 0..124
  const float* Ap = A + (size_t)(bm + am) * K + ak;
  const float* Wp = W + (size_t)bkr * N + bn + bn4;
  float4 aL = *(const float4*)Ap;
  float4 bL = *(const float4*)Wp;
  float acc[8][8];
#pragma unroll
  for (int i = 0; i < 8; ++i)
#pragma unroll
    for (int j = 0; j < 8; ++j) acc[i][j] = 0.f;

  for (int k0 = 0; k0 < K; k0 += 8) {
    As[ak+0][am] = aL.x; As[ak+1][am] = aL.y; As[ak+2][am] = aL.z; As[ak+3][am] = aL.w;
    *(float4*)&Bs[bkr][bn4] = bL;
    __syncthreads();
    if (k0 + 8 < K) {   // prefetch next tiles while computing this one
      aL = *(const float4*)(Ap + k0 + 8);
      bL = *(const float4*)(Wp + (size_t)(k0 + 8) * N);
    }
#pragma unroll
    for (int kk = 0; kk < 8; ++kk) {
      const float4 a0 = *(const float4*)&As[kk][tr];
      const float4 a1 = *(const float4*)&As[kk][tr + 64];
      const float4 b0 = *(const float4*)&Bs[kk][tc];
      const float4 b1 = *(const float4*)&Bs[kk][tc + 64];
      const float av[8] = {a0.x,a0.y,a0.z,a0.w,a1.x,a1.y,a1.z,a1.w};
      const float bv[8] = {b0.x,b0.y,b0.z,b0.w,b1.x,b1.y,b1.z,b1.w};
#pragma unroll
      for (int i = 0; i < 8; ++i)
#pragma unroll
        for (int j = 0; j < 8; ++j) acc[i][j] += av[i] * bv[j];
    }
    __syncthreads();
  }
#pragma unroll
  for (int i = 0; i < 8; ++i) {
    const int m = bm + ((i < 4) ? (tr + i) : (tr + 60 + i));
    const size_t ro = (size_t)m * N;
#pragma unroll
    for (int jq = 0; jq < 2; ++jq) {
      const int n = bn + tc + jq * 64;
      float4 r;
      r.x = acc[i][jq*4+0] + bias[n+0];
      r.y = acc[i][jq*4+1] + bias[n+1];
      r.z = acc[i][jq*4+2] + bias[n+2];
      r.w = acc[i][jq*4+3] + bias[n+3];
      if (Res != nullptr) {
        const float4 rv = *(const float4*)(Res + ro + n);
        r.x += rv.x; r.y += rv.y; r.z += rv.z; r.w += rv.w;
      }
      *(float4*)(C + ro + n) = r;
    }
  }
}

// QKV: three GEMMs fused by blockIdx.z for CU utilization (1152 blocks)
__global__ __launch_bounds__(256) void qkv_kernel(
    const float* __restrict__ x,
    const float* __restrict__ Wq, const float* __restrict__ Wk, const float* __restrict__ Wv,
    const float* __restrict__ bq, const float* __restrict__ bk, const float* __restrict__ bv,
    float* __restrict__ q, float* __restrict__ k, float* __restrict__ v)
{
  const float* W; const float* bias; float* C;
  if (blockIdx.z == 0)      { W = Wq; bias = bq; C = q; }
  else if (blockIdx.z == 1) { W = Wk; bias = bk; C = k; }
  else                      { W = Wv; bias = bv; C = v; }
  gemm128_body(x, W, bias, nullptr, C, ROWS, HID, HID);
}

// out = ctx @ Wo + bo + x(residual)  -> h
__global__ __launch_bounds__(256) void proj_kernel(
    const float* __restrict__ ctx, const float* __restrict__ Wo,
    const float* __restrict__ bo, const float* __restrict__ x, float* __restrict__ h)
{
  gemm128_body(ctx, Wo, bo, x, h, ROWS, HID, HID);
}

// ---------------------------------------------------------------------------
// scores[z, m, n] = (q_bh[m]·k_bh[n] + exp(-0.1*min(|m-n|,5))) / sqrt(D) - 0.1*|m-n|
// per-head 512x512x192 GEMM (B transposed-load), epilogue fuses the bias terms.
// ---------------------------------------------------------------------------
__global__ __launch_bounds__(256) void score_gemm_kernel(
    const float* __restrict__ q, const float* __restrict__ k, float* __restrict__ sc)
{
  __shared__ float As[8][132];
  __shared__ float Bs[8][132];
  const int tid = threadIdx.x;
  const int z  = blockIdx.z;            // b*4+h
  const int b  = z >> 2;
  const int hh = z & 3;
  const int bm = blockIdx.y * 128;      // query rows
  const int bn = blockIdx.x * 128;      // key cols
  const float* qh = q + (size_t)b * SEQ * HID + hh * HDIM;
  const float* kh = k + (size_t)b * SEQ * HID + hh * HDIM;
  float* sch = sc + (size_t)z * SEQ * SEQ;
  const int tr = (tid >> 4) * 4;
  const int tc = (tid & 15) * 4;
  const int am = tid >> 1;
  const int ak = (tid & 1) * 4;
  const int bj = tid >> 1;              // key row within tile
  const int bd = (tid & 1) * 4;         // d offset
  const float* Ap = qh + (size_t)(bm + am) * HID + ak;
  const float* Bp = kh + (size_t)(bn + bj) * HID + bd;
  float4 aL = *(const float4*)Ap;
  float4 bL = *(const float4*)Bp;
  float acc[8][8];
#pragma unroll
  for (int i = 0; i < 8; ++i)
#pragma unroll
    for (int j = 0; j < 8; ++j) acc[i][j] = 0.f;

  for (int k0 = 0; k0 < HDIM; k0 += 8) {
    As[ak+0][am] = aL.x; As[ak+1][am] = aL.y; As[ak+2][am] = aL.z; As[ak+3][am] = aL.w;
    Bs[bd+0][bj] = bL.x; Bs[bd+1][bj] = bL.y; Bs[bd+2][bj] = bL.z; Bs[bd+3][bj] = bL.w;
    __syncthreads();
    if (k0 + 8 < HDIM) {
      aL = *(const float4*)(Ap + k0 + 8);
      bL = *(const float4*)(Bp + k0 + 8);
    }
#pragma unroll
    for (int kk = 0; kk < 8; ++kk) {
      const float4 a0 = *(const float4*)&As[kk][tr];
      const float4 a1 = *(const float4*)&As[kk][tr + 64];
      const float4 b0 = *(const float4*)&Bs[kk][tc];
      const float4 b1 = *(const float4*)&Bs[kk][tc + 64];
      const float av[8] = {a0.x,a0.y,a0.z,a0.w,a1.x,a1.y,a1.z,a1.w};
      const float bv[8] = {b0.x,b0.y,b0.z,b0.w,b1.x,b1.y,b1.z,b1.w};
#pragma unroll
      for (int i = 0; i < 8; ++i)
#pragma unroll
        for (int j = 0; j < 8; ++j) acc[i][j] += av[i] * bv[j];
    }
    __syncthreads();
  }
#pragma unroll
  for (int i = 0; i < 8; ++i) {
    const int m = bm + ((i < 4) ? (tr + i) : (tr + 60 + i));
    const size_t ro = (size_t)m * SEQ;
#pragma unroll
    for (int jq = 0; jq < 2; ++jq) {
      const int n = bn + tc + jq * 64;
      float vv[4];
#pragma unroll
      for (int t = 0; t < 4; ++t) {
        const float dist = fabsf((float)(m - (n + t)));
        const float rel  = __expf(-0.1f * fminf(dist, 5.0f));
        vv[t] = (acc[i][jq*4+t] + rel) * INV_SQRT_D - 0.1f * dist;
      }
      float4 r; r.x = vv[0]; r.y = vv[1]; r.z = vv[2]; r.w = vv[3];
      *(float4*)(sch + ro + n) = r;
    }
  }
}

// in-place row softmax over 512; one wave per row, 4 rows per block
__global__ __launch_bounds__(256) void softmax_kernel(float* __restrict__ sc)
{
  const int blk  = blockIdx.x;           // 0..8191
  const int z    = blk >> 7;
  const int rg   = blk & 127;
  const int tid  = threadIdx.x;
  const int rr   = tid >> 6;
  const int lane = tid & 63;
  const int r    = rg * 4 + rr;
  float* row = sc + (size_t)z * SEQ * SEQ + (size_t)r * SEQ;
  float4 v0 = *(const float4*)(row + lane * 8);
  float4 v1 = *(const float4*)(row + lane * 8 + 4);
  float mx = fmaxf(fmaxf(fmaxf(v0.x,v0.y),fmaxf(v0.z,v0.w)),
                   fmaxf(fmaxf(v1.x,v1.y),fmaxf(v1.z,v1.w)));
#pragma unroll
  for (int o = 32; o > 0; o >>= 1) mx = fmaxf(mx, __shfl_xor(mx, o, 64));
  v0.x = __expf(v0.x - mx); v0.y = __expf(v0.y - mx);
  v0.z = __expf(v0.z - mx); v0.w = __expf(v0.w - mx);
  v1.x = __expf(v1.x - mx); v1.y = __expf(v1.y - mx);
  v1.z = __expf(v1.z - mx); v1.w = __expf(v1.w - mx);
  float s = v0.x+v0.y+v0.z+v0.w+v1.x+v1.y+v1.z+v1.w;
#pragma unroll
  for (int o = 32; o > 0; o >>= 1) s += __shfl_xor(s, o, 64);
  const float inv = 1.0f / s;
  v0.x *= inv; v0.y *= inv; v0.z *= inv; v0.w *= inv;
  v1.x *= inv; v1.y *= inv; v1.z *= inv; v1.w *= inv;
  *(float4*)(row + lane * 8)     = v0;
  *(float4*)(row + lane * 8 + 4) = v1;
}

// ctx[b, m, hh*192 + n] = sum_c probs[z,m,c] * v[b,c,hh*192+n]; 128x64 tile
__global__ __launch_bounds__(256) void pv_gemm_kernel(
    const float* __restrict__ sc, const float* __restrict__ v, float* __restrict__ ctx)
{
  __shared__ float As[8][132];
  __shared__ float Bs[8][68];
  const int tid = threadIdx.x;
  const int z = blockIdx.z; const int b = z >> 2; const int hh = z & 3;
  const int bm = blockIdx.y * 128;
  const int bn = blockIdx.x * 64;
  const float* Ph = sc + (size_t)z * SEQ * SEQ;
  const float* Vh = v + (size_t)b * SEQ * HID + hh * HDIM;
  float* Ch = ctx + (size_t)b * SEQ * HID + hh * HDIM;
  const int tr = (tid >> 4) * 4;
  const int tc = (tid & 15) * 4;
  const int am = tid >> 1;
  const int ak = (tid & 1) * 4;
  const int vk = tid >> 4;            // 0..7 (threads <128)
  const int vn = (tid & 15) * 4;
  const float* Ap = Ph + (size_t)(bm + am) * SEQ + ak;
  const float* Vp = Vh + (size_t)vk * HID + bn + vn;
  float4 aL = *(const float4*)Ap;
  float4 bL = make_float4(0.f,0.f,0.f,0.f);
  if (tid < 128) bL = *(const float4*)Vp;
  float acc[8][4];
#pragma unroll
  for (int i = 0; i < 8; ++i)
#pragma unroll
    for (int j = 0; j < 4; ++j) acc[i][j] = 0.f;

  for (int k0 = 0; k0 < SEQ; k0 += 8) {
    As[ak+0][am] = aL.x; As[ak+1][am] = aL.y; As[ak+2][am] = aL.z; As[ak+3][am] = aL.w;
    if (tid < 128) { *(float4*)&Bs[vk][vn] = bL; }
    __syncthreads();
    if (k0 + 8 < SEQ) {
      aL = *(const float4*)(Ap + k0 + 8);
      if (tid < 128) bL = *(const float4*)(Vp + (size_t)(k0 + 8) * HID);
    }
#pragma unroll
    for (int kk = 0; kk < 8; ++kk) {
      const float4 a0 = *(const float4*)&As[kk][tr];
      const float4 a1 = *(const float4*)&As[kk][tr + 64];
      const float4 b0 = *(const float4*)&Bs[kk][tc];
      const float av[8] = {a0.x,a0.y,a0.z,a0.w,a1.x,a1.y,a1.z,a1.w};
      const float bv4[4] = {b0.x,b0.y,b0.z,b0.w};
#pragma unroll
      for (int i = 0; i < 8; ++i)
#pragma unroll
        for (int j = 0; j < 4; ++j) acc[i][j] += av[i] * bv4[j];
    }
    __syncthreads();
  }
#pragma unroll
  for (int i = 0; i < 8; ++i) {
    const int m = bm + ((i < 4) ? (tr + i) : (tr + 60 + i));
    float4 r; r.x = acc[i][0]; r.y = acc[i][1]; r.z = acc[i][2]; r.w = acc[i][3];
    *(float4*)(Ch + (size_t)m * HID + bn + tc) = r;
  }
}

// LayerNorm(768) + span_logits = hn @ Ws[768,9] + bs, one block per row
__global__ __launch_bounds__(256) void ln_logits_kernel(
    const float* __restrict__ h, const float* __restrict__ g,
    const float* __restrict__ bta, const float* __restrict__ Ws,
    const float* __restrict__ bsv, float* __restrict__ span)
{
  const int row = blockIdx.x;
  const int tid = threadIdx.x;
  const float* hr = h + (size_t)row * HID;
  const float x0 = hr[tid], x1 = hr[tid + 256], x2 = hr[tid + 512];
  float s  = x0 + x1 + x2;
  float sq = x0*x0 + x1*x1 + x2*x2;
#pragma unroll
  for (int o = 32; o > 0; o >>= 1) { s += __shfl_down(s, o, 64); sq += __shfl_down(sq, o, 64); }
  __shared__ float red[8];
  __shared__ float smu, srs;
  const int wid = tid >> 6, lid = tid & 63;
  if (lid == 0) { red[wid] = s; red[4 + wid] = sq; }
  __syncthreads();
  if (tid == 0) {
    const float ts = red[0] + red[1] + red[2] + red[3];
    const float tq = red[4] + red[5] + red[6] + red[7];
    const float mu = ts / 768.0f;
    const float var = tq / 768.0f - mu * mu;
    smu = mu; srs = rsqrtf(var + 1e-5f);
  }
  __syncthreads();
  const float mu = smu, rs = srs;
  const float n0 = (x0 - mu) * rs * g[tid]       + bta[tid];
  const float n1 = (x1 - mu) * rs * g[tid + 256] + bta[tid + 256];
  const float n2 = (x2 - mu) * rs * g[tid + 512] + bta[tid + 512];
  float pl[9];
#pragma unroll
  for (int l = 0; l < 9; ++l)
    pl[l] = n0 * Ws[(size_t)tid*9 + l]
          + n1 * Ws[(size_t)(tid+256)*9 + l]
          + n2 * Ws[(size_t)(tid+512)*9 + l];
#pragma unroll
  for (int l = 0; l < 9; ++l)
#pragma unroll
    for (int o = 32; o > 0; o >>= 1) pl[l] += __shfl_down(pl[l], o, 64);
  __shared__ float lred[4][9];
  if (lid == 0) {
#pragma unroll
    for (int l = 0; l < 9; ++l) lred[wid][l] = pl[l];
  }
  __syncthreads();
  if (tid < 9) {
    const float t = lred[0][tid] + lred[1][tid] + lred[2][tid] + lred[3][tid] + bsv[tid];
    span[(size_t)row * 9 + tid] = t;
  }
}

// final bump: if argmax(span[b, j-1]) == 1 (first-max tiebreak), out[b,j,2] += 2*eb[2]
__global__ __launch_bounds__(256) void bump_kernel(
    const float* __restrict__ span, const float* __restrict__ eb, float* __restrict__ out)
{
  const int idx = blockIdx.x * 256 + threadIdx.x;   // 0..8191
  if (idx >= ROWS) return;
  const int j = idx & (SEQ - 1);
  const float* sl = span + (size_t)idx * 9;
  float v[9];
#pragma unroll
  for (int l = 0; l < 9; ++l) v[l] = sl[l];
  if (j >= 1) {
    const float* sp = sl - 9;
    float m = sp[0]; int am = 0;
#pragma unroll
    for (int l = 1; l < 9; ++l) { const float t = sp[l]; if (t > m) { m = t; am = l; } }
    if (am == 1) v[2] += 2.0f * eb[2];
  }
#pragma unroll
  for (int l = 0; l < 9; ++l) out[(size_t)idx * 9 + l] = v[l];
}

extern "C" void kernel_launch(void* const* d_in, const int* in_sizes, int n_in,
                              void* d_out, int out_size, void* d_ws, size_t ws_size,
                              hipStream_t stream)
{
  (void)in_sizes; (void)n_in; (void)out_size; (void)ws_size;
  const float* x   = (const float*)d_in[0];
  const float* Wq  = (const float*)d_in[1];
  const float* bq  = (const float*)d_in[2];
  const float* Wk  = (const float*)d_in[3];
  const float* bk  = (const float*)d_in[4];
  const float* Wv  = (const float*)d_in[5];
  const float* bv  = (const float*)d_in[6];
  const float* Wo  = (const float*)d_in[7];
  const float* bo  = (const float*)d_in[8];
  const float* lng = (const float*)d_in[9];
  const float* lnb = (const float*)d_in[10];
  const float* Ws  = (const float*)d_in[11];
  const float* bs  = (const float*)d_in[12];
  const float* eb  = (const float*)d_in[13];
  float* out = (float*)d_out;

  float* ws = (float*)d_ws;
  const size_t NBIG = (size_t)ROWS * HID;           // 6291456
  float* qb   = ws;
  float* kb   = qb + NBIG;
  float* vb   = kb + NBIG;
  float* ctxb = vb + NBIG;
  float* scb  = ctxb + NBIG;                        // 64*512*512 = 16777216
  float* spanb = scb + (size_t)64 * SEQ * SEQ;      // 73728
  float* hb = qb;                                   // q dead after score_gemm; reuse for h

  qkv_kernel<<<dim3(6, 64, 3), 256, 0, stream>>>(x, Wq, Wk, Wv, bq, bk, bv, qb, kb, vb);
  score_gemm_kernel<<<dim3(4, 4, 64), 256, 0, stream>>>(qb, kb, scb);
  softmax_kernel<<<dim3(8192), 256, 0, stream>>>(scb);
  pv_gemm_kernel<<<dim3(3, 4, 64), 256, 0, stream>>>(scb, vb, ctxb);
  proj_kernel<<<dim3(6, 64, 1), 256, 0, stream>>>(ctxb, Wo, bo, x, hb);
  ln_logits_kernel<<<dim3(ROWS), 256, 0, stream>>>(hb, lng, lnb, Ws, bs, spanb);
  bump_kernel<<<dim3(ROWS / 256), 256, 0, stream>>>(spanb, eb, out);
}

// Round 2
// 431.948 us; speedup vs baseline: 1.8524x; 1.8524x over previous
//
#include <hip/hip_runtime.h>
#include <math.h>

#define SEQ 512
#define HID 768
#define NBATCH 16
#define ROWS 8192
#define INV_SQRT_D 0.07216878364870323f

typedef short s8v __attribute__((ext_vector_type(8)));
typedef float f4v __attribute__((ext_vector_type(4)));
typedef unsigned short u16;

// ---- bf16 helpers (RNE) ----
__device__ __forceinline__ u16 f2bf(float f) {
  unsigned u = __builtin_bit_cast(unsigned, f);
  unsigned r = u + 0x7FFFu + ((u >> 16) & 1u);
  return (u16)(r >> 16);
}
__device__ __forceinline__ float bf2f(u16 s) {
  unsigned u = ((unsigned)s) << 16;
  return __builtin_bit_cast(float, u);
}

// async global->LDS, 16B per lane; lds dest is wave-uniform base + lane*16
__device__ __forceinline__ void gl2lds16(const u16* g, u16* l) {
  __builtin_amdgcn_global_load_lds((const __attribute__((address_space(1))) void*)g,
                                   (__attribute__((address_space(3))) void*)l, 16, 0, 0);
}

// ---------------------------------------------------------------------------
// Core: 128x128 tile, BK=32, split-bf16 (hi/lo), 256 threads = 4 waves (2x2).
// LDS: Ah[128x32] Al Bh Bl  (each 4096 u16 = 8KB, total 32KB).
// A source: row-major [m][k] (k-contig). B source: row-major [n][k] (k-contig).
// acc += Ah*Bh + Ah*Bl + Al*Bh  over KSTEPS*32 logical K.
// ---------------------------------------------------------------------------
template <int KSTEPS>
__device__ __forceinline__ void mm_core128(
    const u16* __restrict__ Ah, const u16* __restrict__ Al, const int lda,
    const u16* __restrict__ Bh, const u16* __restrict__ Bl, const int ldb,
    u16* lds, f4v (&acc)[4][4])
{
  const int tid = threadIdx.x;
  const int w = tid >> 6, ln = tid & 63;
  // staging: wave w owns tile w
  const u16* src; int ld;
  if (w == 0)      { src = Ah; ld = lda; }
  else if (w == 1) { src = Al; ld = lda; }
  else if (w == 2) { src = Bh; ld = ldb; }
  else             { src = Bl; ld = ldb; }
  u16* myTile = lds + w * 4096;
  const int srow = ln >> 2;            // 0..15 within 16-row group
  const int schunk = (ln & 3) * 8;     // k offset in elems
  const int ml = ln & 15, quad = ln >> 4;
  const int fo = quad * 8;
  const int wr = (w >> 1) * 64, wc = (w & 1) * 64;

  for (int ks = 0; ks < KSTEPS; ++ks) {
    const int k0 = ks * 32;
    const u16* sb = src + (size_t)srow * ld + k0 + schunk;
#pragma unroll
    for (int t = 0; t < 8; ++t)
      gl2lds16(sb + (size_t)(t * 16) * ld, myTile + t * 512);
    __syncthreads();
    s8v ah[4], al[4], bh[4], bl[4];
#pragma unroll
    for (int i = 0; i < 4; ++i) {
      const int ra = (wr + i * 16 + ml) * 32 + fo;
      ah[i] = *(const s8v*)&lds[ra];
      al[i] = *(const s8v*)&lds[4096 + ra];
      const int rb = (wc + i * 16 + ml) * 32 + fo;
      bh[i] = *(const s8v*)&lds[8192 + rb];
      bl[i] = *(const s8v*)&lds[12288 + rb];
    }
#pragma unroll
    for (int i = 0; i < 4; ++i)
#pragma unroll
      for (int j = 0; j < 4; ++j)
        acc[i][j] = __builtin_amdgcn_mfma_f32_16x16x32_bf16(ah[i], bh[j], acc[i][j], 0, 0, 0);
#pragma unroll
    for (int i = 0; i < 4; ++i)
#pragma unroll
      for (int j = 0; j < 4; ++j)
        acc[i][j] = __builtin_amdgcn_mfma_f32_16x16x32_bf16(ah[i], bl[j], acc[i][j], 0, 0, 0);
#pragma unroll
    for (int i = 0; i < 4; ++i)
#pragma unroll
      for (int j = 0; j < 4; ++j)
        acc[i][j] = __builtin_amdgcn_mfma_f32_16x16x32_bf16(al[i], bh[j], acc[i][j], 0, 0, 0);
    __syncthreads();
  }
}

// ---- prep: split x into hi/lo bf16 ----
__global__ __launch_bounds__(256) void splitx(const float* __restrict__ x,
                                              u16* __restrict__ xh, u16* __restrict__ xl)
{
  const int i = blockIdx.x * 256 + threadIdx.x;       // per float4
  const float4 v = ((const float4*)x)[i];
  u16 h0 = f2bf(v.x), h1 = f2bf(v.y), h2 = f2bf(v.z), h3 = f2bf(v.w);
  ushort4 hv = make_ushort4(h0, h1, h2, h3);
  ushort4 lv = make_ushort4(f2bf(v.x - bf2f(h0)), f2bf(v.y - bf2f(h1)),
                            f2bf(v.z - bf2f(h2)), f2bf(v.w - bf2f(h3)));
  ((ushort4*)xh)[i] = hv;
  ((ushort4*)xl)[i] = lv;
}

// ---- prep: transpose + split weights: WT[z][n][k] = W_z[k][n] ----
__global__ __launch_bounds__(256) void wsplit(
    const float* __restrict__ Wq, const float* __restrict__ Wk,
    const float* __restrict__ Wv, const float* __restrict__ Wo,
    u16* __restrict__ WTh, u16* __restrict__ WTl)
{
  __shared__ float t[32][33];
  const int z = blockIdx.z;
  const float* W = (z == 0) ? Wq : (z == 1) ? Wk : (z == 2) ? Wv : Wo;
  const int n0 = blockIdx.x * 32, k0 = blockIdx.y * 32;
  const int tx = threadIdx.x & 31, ty = threadIdx.x >> 5;     // ty 0..7
#pragma unroll
  for (int i = 0; i < 4; ++i)
    t[ty + 8 * i][tx] = W[(size_t)(k0 + ty + 8 * i) * HID + n0 + tx];
  __syncthreads();
#pragma unroll
  for (int i = 0; i < 4; ++i) {
    const float v = t[tx][ty + 8 * i];                        // W[k0+tx][n0+ty+8i]
    const size_t idx = (size_t)z * HID * HID + (size_t)(n0 + ty + 8 * i) * HID + k0 + tx;
    const u16 hi = f2bf(v);
    WTh[idx] = hi;
    WTl[idx] = f2bf(v - bf2f(hi));
  }
}

// ---- QKV GEMM: z=0 -> q split, z=1 -> k split, z=2 -> v fp32 temp ----
__global__ __launch_bounds__(256) void qkv_mm(
    const u16* __restrict__ xh, const u16* __restrict__ xl,
    const u16* __restrict__ WTh, const u16* __restrict__ WTl,
    const float* __restrict__ bq, const float* __restrict__ bk, const float* __restrict__ bv,
    u16* __restrict__ qh, u16* __restrict__ ql,
    u16* __restrict__ kh, u16* __restrict__ kl, float* __restrict__ vtmp)
{
  __shared__ u16 lds[16384];
  const int z = blockIdx.z;
  const int bm = blockIdx.y * 128, bn = blockIdx.x * 128;
  const size_t wtoff = (size_t)z * HID * HID + (size_t)bn * HID;
  f4v acc[4][4];
#pragma unroll
  for (int i = 0; i < 4; ++i)
#pragma unroll
    for (int j = 0; j < 4; ++j) acc[i][j] = (f4v)0.f;
  mm_core128<24>(xh + (size_t)bm * HID, xl + (size_t)bm * HID, HID,
                 WTh + wtoff, WTl + wtoff, HID, lds, acc);
  const int tid = threadIdx.x, w = tid >> 6, ln = tid & 63;
  const int ml = ln & 15, quad = ln >> 4;
  const int wr = (w >> 1) * 64, wc = (w & 1) * 64;
  const float* bias = (z == 0) ? bq : (z == 1) ? bk : bv;
#pragma unroll
  for (int i = 0; i < 4; ++i)
#pragma unroll
    for (int j = 0; j < 4; ++j) {
      const int gcol = bn + wc + j * 16 + ml;
      const float bv_ = bias[gcol];
#pragma unroll
      for (int r = 0; r < 4; ++r) {
        const int grow = bm + wr + i * 16 + quad * 4 + r;
        const float v = acc[i][j][r] + bv_;
        const size_t idx = (size_t)grow * HID + gcol;
        if (z == 2) {
          vtmp[idx] = v;
        } else {
          const u16 hi = f2bf(v);
          const u16 lo = f2bf(v - bf2f(hi));
          if (z == 0) { qh[idx] = hi; ql[idx] = lo; }
          else        { kh[idx] = hi; kl[idx] = lo; }
        }
      }
    }
}

// ---- prep: transpose + split v: vT[b][n][c] = vtmp[b][c][n] ----
__global__ __launch_bounds__(256) void vtrans(const float* __restrict__ vtmp,
                                              u16* __restrict__ vTh, u16* __restrict__ vTl)
{
  __shared__ float t[32][33];
  const int b = blockIdx.z, n0 = blockIdx.x * 32, c0 = blockIdx.y * 32;
  const int tx = threadIdx.x & 31, ty = threadIdx.x >> 5;
  const float* src = vtmp + (size_t)b * SEQ * HID;
#pragma unroll
  for (int i = 0; i < 4; ++i)
    t[ty + 8 * i][tx] = src[(size_t)(c0 + ty + 8 * i) * HID + n0 + tx];
  __syncthreads();
#pragma unroll
  for (int i = 0; i < 4; ++i) {
    const float v = t[tx][ty + 8 * i];                        // v[c0+tx][n0+ty+8i]
    const size_t idx = (size_t)b * HID * SEQ + (size_t)(n0 + ty + 8 * i) * SEQ + c0 + tx;
    const u16 hi = f2bf(v);
    vTh[idx] = hi;
    vTl[idx] = f2bf(v - bf2f(hi));
  }
}

// ---- scores GEMM + fused rel-bias/scale/dist-mask epilogue (fp32 out) ----
__global__ __launch_bounds__(256) void scores_mm(
    const u16* __restrict__ qh, const u16* __restrict__ ql,
    const u16* __restrict__ kh, const u16* __restrict__ kl, float* __restrict__ sc)
{
  __shared__ u16 lds[16384];
  const int z = blockIdx.z, b = z >> 2, hh = z & 3;
  const int bm = blockIdx.y * 128, bn = blockIdx.x * 128;
  const size_t abase = (size_t)(b * SEQ + bm) * HID + hh * 192;
  const size_t bbase = (size_t)(b * SEQ + bn) * HID + hh * 192;
  f4v acc[4][4];
#pragma unroll
  for (int i = 0; i < 4; ++i)
#pragma unroll
    for (int j = 0; j < 4; ++j) acc[i][j] = (f4v)0.f;
  mm_core128<6>(qh + abase, ql + abase, HID, kh + bbase, kl + bbase, HID, lds, acc);
  const int tid = threadIdx.x, w = tid >> 6, ln = tid & 63;
  const int ml = ln & 15, quad = ln >> 4;
  const int wr = (w >> 1) * 64, wc = (w & 1) * 64;
  float* sch = sc + (size_t)z * SEQ * SEQ;
#pragma unroll
  for (int i = 0; i < 4; ++i)
#pragma unroll
    for (int j = 0; j < 4; ++j) {
      const int scol = bn + wc + j * 16 + ml;
#pragma unroll
      for (int r = 0; r < 4; ++r) {
        const int srow = bm + wr + i * 16 + quad * 4 + r;
        const float dist = fabsf((float)(srow - scol));
        const float rel = __expf(-0.1f * fminf(dist, 5.0f));
        sch[(size_t)srow * SEQ + scol] =
            (acc[i][j][r] + rel) * INV_SQRT_D - 0.1f * dist;
      }
    }
}

// ---- softmax in-place, writes probs hi/lo bf16 into the same row bytes ----
__global__ __launch_bounds__(256) void softmax_split(float* __restrict__ sc)
{
  const int blk = blockIdx.x;                  // 0..8191
  const int z = blk >> 7, rg = blk & 127;
  const int tid = threadIdx.x;
  const int rr = tid >> 6, lane = tid & 63;
  const int r = rg * 4 + rr;
  float* row = sc + (size_t)z * SEQ * SEQ + (size_t)r * SEQ;
  float4 v0 = *(const float4*)(row + lane * 8);
  float4 v1 = *(const float4*)(row + lane * 8 + 4);
  float mx = fmaxf(fmaxf(fmaxf(v0.x, v0.y), fmaxf(v0.z, v0.w)),
                   fmaxf(fmaxf(v1.x, v1.y), fmaxf(v1.z, v1.w)));
#pragma unroll
  for (int o = 32; o > 0; o >>= 1) mx = fmaxf(mx, __shfl_xor(mx, o, 64));
  v0.x = __expf(v0.x - mx); v0.y = __expf(v0.y - mx);
  v0.z = __expf(v0.z - mx); v0.w = __expf(v0.w - mx);
  v1.x = __expf(v1.x - mx); v1.y = __expf(v1.y - mx);
  v1.z = __expf(v1.z - mx); v1.w = __expf(v1.w - mx);
  float s = v0.x + v0.y + v0.z + v0.w + v1.x + v1.y + v1.z + v1.w;
#pragma unroll
  for (int o = 32; o > 0; o >>= 1) s += __shfl_xor(s, o, 64);
  const float inv = 1.0f / s;
  float p[8] = {v0.x * inv, v0.y * inv, v0.z * inv, v0.w * inv,
                v1.x * inv, v1.y * inv, v1.z * inv, v1.w * inv};
  u16 hi[8], lo[8];
#pragma unroll
  for (int t = 0; t < 8; ++t) {
    hi[t] = f2bf(p[t]);
    lo[t] = f2bf(p[t] - bf2f(hi[t]));
  }
  u16* ph = (u16*)row;                          // [0,512) hi, [512,1024) lo
  ushort4* d0 = (ushort4*)&ph[lane * 8];
  d0[0] = make_ushort4(hi[0], hi[1], hi[2], hi[3]);
  d0[1] = make_ushort4(hi[4], hi[5], hi[6], hi[7]);
  ushort4* d1 = (ushort4*)&ph[512 + lane * 8];
  d1[0] = make_ushort4(lo[0], lo[1], lo[2], lo[3]);
  d1[1] = make_ushort4(lo[4], lo[5], lo[6], lo[7]);
}

// ---- PV GEMM: 64x192 tile, probs(split) @ vT(split) -> ctx split ----
__global__ __launch_bounds__(256) void pv_mm(
    const u16* __restrict__ pbase, const u16* __restrict__ vTh, const u16* __restrict__ vTl,
    u16* __restrict__ ch, u16* __restrict__ cl)
{
  __shared__ u16 lds[16384];   // Ah@0(2048) Al@2048 Bh@4096(6144) Bl@10240(6144)
  const int z = blockIdx.y, b = z >> 2, hh = z & 3;
  const int bm = blockIdx.x * 64;
  const u16* ah_g = pbase + (size_t)z * SEQ * 1024 + (size_t)bm * 1024;  // ld 1024
  const u16* al_g = ah_g + 512;
  const u16* bh_g = vTh + (size_t)b * HID * SEQ + (size_t)(hh * 192) * SEQ;  // ld 512
  const u16* bl_g = vTl + (size_t)b * HID * SEQ + (size_t)(hh * 192) * SEQ;
  const int tid = threadIdx.x, w = tid >> 6, ln = tid & 63;
  const int srow = ln >> 2, schunk = (ln & 3) * 8;
  const int ml = ln & 15, quad = ln >> 4, fo = quad * 8;
  f4v acc[12];
#pragma unroll
  for (int j = 0; j < 12; ++j) acc[j] = (f4v)0.f;

  for (int ks = 0; ks < 16; ++ks) {
    const int k0 = ks * 32;
#pragma unroll
    for (int s = 0; s < 8; ++s) {
      const int p = w * 8 + s;
      const u16* g; u16* l;
      if (p < 4)       { g = ah_g + (size_t)(p * 16 + srow) * 1024 + k0 + schunk; l = lds + p * 512; }
      else if (p < 8)  { const int t = p - 4;  g = al_g + (size_t)(t * 16 + srow) * 1024 + k0 + schunk; l = lds + 2048 + t * 512; }
      else if (p < 20) { const int t = p - 8;  g = bh_g + (size_t)(t * 16 + srow) * 512 + k0 + schunk; l = lds + 4096 + t * 512; }
      else             { const int t = p - 20; g = bl_g + (size_t)(t * 16 + srow) * 512 + k0 + schunk; l = lds + 10240 + t * 512; }
      gl2lds16(g, l);
    }
    __syncthreads();
    const int ra = (w * 16 + ml) * 32 + fo;
    const s8v a_h = *(const s8v*)&lds[ra];
    const s8v a_l = *(const s8v*)&lds[2048 + ra];
    s8v bh[12], bl[12];
#pragma unroll
    for (int j = 0; j < 12; ++j) {
      const int rb = (j * 16 + ml) * 32 + fo;
      bh[j] = *(const s8v*)&lds[4096 + rb];
      bl[j] = *(const s8v*)&lds[10240 + rb];
    }
#pragma unroll
    for (int j = 0; j < 12; ++j)
      acc[j] = __builtin_amdgcn_mfma_f32_16x16x32_bf16(a_h, bh[j], acc[j], 0, 0, 0);
#pragma unroll
    for (int j = 0; j < 12; ++j)
      acc[j] = __builtin_amdgcn_mfma_f32_16x16x32_bf16(a_h, bl[j], acc[j], 0, 0, 0);
#pragma unroll
    for (int j = 0; j < 12; ++j)
      acc[j] = __builtin_amdgcn_mfma_f32_16x16x32_bf16(a_l, bh[j], acc[j], 0, 0, 0);
    __syncthreads();
  }
#pragma unroll
  for (int j = 0; j < 12; ++j) {
    const int gcol = hh * 192 + j * 16 + ml;
#pragma unroll
    for (int r = 0; r < 4; ++r) {
      const int m = bm + w * 16 + quad * 4 + r;
      const float v = acc[j][r];
      const size_t idx = (size_t)(b * SEQ + m) * HID + gcol;
      const u16 hi = f2bf(v);
      ch[idx] = hi;
      cl[idx] = f2bf(v - bf2f(hi));
    }
  }
}

// ---- projection GEMM + bias + residual -> h fp32 ----
__global__ __launch_bounds__(256) void proj_mm(
    const u16* __restrict__ ch, const u16* __restrict__ cl,
    const u16* __restrict__ WTh, const u16* __restrict__ WTl,
    const float* __restrict__ bo, const float* __restrict__ x, float* __restrict__ h)
{
  __shared__ u16 lds[16384];
  const int bm = blockIdx.y * 128, bn = blockIdx.x * 128;
  const size_t wtoff = (size_t)3 * HID * HID + (size_t)bn * HID;
  f4v acc[4][4];
#pragma unroll
  for (int i = 0; i < 4; ++i)
#pragma unroll
    for (int j = 0; j < 4; ++j) acc[i][j] = (f4v)0.f;
  mm_core128<24>(ch + (size_t)bm * HID, cl + (size_t)bm * HID, HID,
                 WTh + wtoff, WTl + wtoff, HID, lds, acc);
  const int tid = threadIdx.x, w = tid >> 6, ln = tid & 63;
  const int ml = ln & 15, quad = ln >> 4;
  const int wr = (w >> 1) * 64, wc = (w & 1) * 64;
#pragma unroll
  for (int i = 0; i < 4; ++i)
#pragma unroll
    for (int j = 0; j < 4; ++j) {
      const int gcol = bn + wc + j * 16 + ml;
      const float bv_ = bo[gcol];
#pragma unroll
      for (int r = 0; r < 4; ++r) {
        const int grow = bm + wr + i * 16 + quad * 4 + r;
        const size_t idx = (size_t)grow * HID + gcol;
        h[idx] = acc[i][j][r] + bv_ + x[idx];
      }
    }
}

// ---- LayerNorm + 9-label classifier ----
__global__ __launch_bounds__(256) void ln_logits_kernel(
    const float* __restrict__ h, const float* __restrict__ g,
    const float* __restrict__ bta, const float* __restrict__ Ws,
    const float* __restrict__ bsv, float* __restrict__ span)
{
  const int row = blockIdx.x;
  const int tid = threadIdx.x;
  const float* hr = h + (size_t)row * HID;
  const float x0 = hr[tid], x1 = hr[tid + 256], x2 = hr[tid + 512];
  float s = x0 + x1 + x2;
  float sq = x0 * x0 + x1 * x1 + x2 * x2;
#pragma unroll
  for (int o = 32; o > 0; o >>= 1) { s += __shfl_down(s, o, 64); sq += __shfl_down(sq, o, 64); }
  __shared__ float red[8];
  __shared__ float smu, srs;
  const int wid = tid >> 6, lid = tid & 63;
  if (lid == 0) { red[wid] = s; red[4 + wid] = sq; }
  __syncthreads();
  if (tid == 0) {
    const float ts = red[0] + red[1] + red[2] + red[3];
    const float tq = red[4] + red[5] + red[6] + red[7];
    const float mu = ts / 768.0f;
    const float var = tq / 768.0f - mu * mu;
    smu = mu; srs = rsqrtf(var + 1e-5f);
  }
  __syncthreads();
  const float mu = smu, rs = srs;
  const float n0 = (x0 - mu) * rs * g[tid] + bta[tid];
  const float n1 = (x1 - mu) * rs * g[tid + 256] + bta[tid + 256];
  const float n2 = (x2 - mu) * rs * g[tid + 512] + bta[tid + 512];
  float pl[9];
#pragma unroll
  for (int l = 0; l < 9; ++l)
    pl[l] = n0 * Ws[(size_t)tid * 9 + l]
          + n1 * Ws[(size_t)(tid + 256) * 9 + l]
          + n2 * Ws[(size_t)(tid + 512) * 9 + l];
#pragma unroll
  for (int l = 0; l < 9; ++l)
#pragma unroll
    for (int o = 32; o > 0; o >>= 1) pl[l] += __shfl_down(pl[l], o, 64);
  __shared__ float lred[4][9];
  if (lid == 0) {
#pragma unroll
    for (int l = 0; l < 9; ++l) lred[wid][l] = pl[l];
  }
  __syncthreads();
  if (tid < 9) {
    span[(size_t)row * 9 + tid] =
        lred[0][tid] + lred[1][tid] + lred[2][tid] + lred[3][tid] + bsv[tid];
  }
}

// ---- entity-bias bump ----
__global__ __launch_bounds__(256) void bump_kernel(
    const float* __restrict__ span, const float* __restrict__ eb, float* __restrict__ out)
{
  const int idx = blockIdx.x * 256 + threadIdx.x;
  if (idx >= ROWS) return;
  const int j = idx & (SEQ - 1);
  const float* sl = span + (size_t)idx * 9;
  float v[9];
#pragma unroll
  for (int l = 0; l < 9; ++l) v[l] = sl[l];
  if (j >= 1) {
    const float* sp = sl - 9;
    float m = sp[0]; int am = 0;
#pragma unroll
    for (int l = 1; l < 9; ++l) { const float t = sp[l]; if (t > m) { m = t; am = l; } }
    if (am == 1) v[2] += 2.0f * eb[2];
  }
#pragma unroll
  for (int l = 0; l < 9; ++l) out[(size_t)idx * 9 + l] = v[l];
}

extern "C" void kernel_launch(void* const* d_in, const int* in_sizes, int n_in,
                              void* d_out, int out_size, void* d_ws, size_t ws_size,
                              hipStream_t stream)
{
  (void)in_sizes; (void)n_in; (void)out_size; (void)ws_size;
  const float* x   = (const float*)d_in[0];
  const float* Wq  = (const float*)d_in[1];
  const float* bq  = (const float*)d_in[2];
  const float* Wk  = (const float*)d_in[3];
  const float* bk  = (const float*)d_in[4];
  const float* Wv  = (const float*)d_in[5];
  const float* bv  = (const float*)d_in[6];
  const float* Wo  = (const float*)d_in[7];
  const float* bo  = (const float*)d_in[8];
  const float* lng = (const float*)d_in[9];
  const float* lnb = (const float*)d_in[10];
  const float* Ws  = (const float*)d_in[11];
  const float* bs  = (const float*)d_in[12];
  const float* eb  = (const float*)d_in[13];
  float* out = (float*)d_out;

  char* ws = (char*)d_ws;
  // byte offsets (all 256-aligned); total 152,338,432 B
  u16* xh  = (u16*)(ws + 0);                       // 12,582,912
  u16* xl  = (u16*)(ws + 12582912);                // 12,582,912
  u16* vTh = xh;                                   // reuse x region after qkv
  u16* vTl = xl;
  u16* WTh = (u16*)(ws + 25165824);                // 4,718,592
  u16* WTl = (u16*)(ws + 29884416);                // 4,718,592
  u16* qh  = (u16*)(ws + 34603008);                // 12,582,912
  u16* ql  = (u16*)(ws + 47185920);
  u16* kh  = (u16*)(ws + 59768832);
  u16* kl  = (u16*)(ws + 72351744);
  float* scb = (float*)(ws + 84934656);            // 67,108,864 (also vtmp, then h)
  float* spanb = (float*)(ws + 152043520);         // 294,912
  float* vtmp = scb;
  float* hb = scb;
  u16* ctxh = qh;                                  // q dead after scores
  u16* ctxl = ql;

  splitx<<<dim3(1572864 / 256), 256, 0, stream>>>(x, xh, xl);
  wsplit<<<dim3(24, 24, 4), 256, 0, stream>>>(Wq, Wk, Wv, Wo, WTh, WTl);
  qkv_mm<<<dim3(6, 64, 3), 256, 0, stream>>>(xh, xl, WTh, WTl, bq, bk, bv,
                                             qh, ql, kh, kl, vtmp);
  vtrans<<<dim3(24, 16, 16), 256, 0, stream>>>(vtmp, vTh, vTl);
  scores_mm<<<dim3(4, 4, 64), 256, 0, stream>>>(qh, ql, kh, kl, scb);
  softmax_split<<<dim3(8192), 256, 0, stream>>>(scb);
  pv_mm<<<dim3(8, 64), 256, 0, stream>>>((const u16*)scb, vTh, vTl, ctxh, ctxl);
  proj_mm<<<dim3(6, 64), 256, 0, stream>>>(ctxh, ctxl, WTh, WTl, bo, x, hb);
  ln_logits_kernel<<<dim3(ROWS), 256, 0, stream>>>(hb, lng, lnb, Ws, bs, spanb);
  bump_kernel<<<dim3(ROWS / 256), 256, 0, stream>>>(spanb, eb, out);
}

// Round 3
// 426.849 us; speedup vs baseline: 1.8745x; 1.0119x over previous
//
#include <hip/hip_runtime.h>
#include <math.h>

#define SEQ 512
#define HID 768
#define NBATCH 16
#define ROWS 8192
#define INV_SQRT_D 0.07216878364870323f

typedef short s8v __attribute__((ext_vector_type(8)));
typedef float f4v __attribute__((ext_vector_type(4)));
typedef unsigned short u16;

// ---- bf16 helpers (RNE) ----
__device__ __forceinline__ u16 f2bf(float f) {
  unsigned u = __builtin_bit_cast(unsigned, f);
  unsigned r = u + 0x7FFFu + ((u >> 16) & 1u);
  return (u16)(r >> 16);
}
__device__ __forceinline__ float bf2f(u16 s) {
  unsigned u = ((unsigned)s) << 16;
  return __builtin_bit_cast(float, u);
}

// async global->LDS, 16B per lane; lds dest is wave-uniform base + lane*16
__device__ __forceinline__ void gl2lds16(const u16* g, u16* l) {
  __builtin_amdgcn_global_load_lds((const __attribute__((address_space(1))) void*)g,
                                   (__attribute__((address_space(3))) void*)l, 16, 0, 0);
}

// ---------------------------------------------------------------------------
// LDS tile layout with chunk swizzle: tile is 128 rows x 32 u16 (BK=32).
// Logical (row, chunk=k>>3) stored at row*32 + ((chunk + (row>>1))&3)*8.
// - staging: each 4-lane group reads a permutation of one 64B global segment
//   (coalescing preserved), DMA writes stay contiguous (wave base + lane*16).
// - fragment ds_read_b128: per 8-lane phase, byte offsets mod 128 are
//   {0,64,16,80,32,96,48,112} -> all 32 banks exactly once, ZERO conflicts.
// ---------------------------------------------------------------------------
template <int KSTEPS>
__device__ __forceinline__ void mm_core128(
    const u16* __restrict__ Ah, const u16* __restrict__ Al, const int lda,
    const u16* __restrict__ Bh, const u16* __restrict__ Bl, const int ldb,
    u16* lds, f4v (&acc)[4][4])
{
  const int tid = threadIdx.x;
  const int w = tid >> 6, ln = tid & 63;
  // staging: wave w owns tile w
  const u16* src; int ld;
  if (w == 0)      { src = Ah; ld = lda; }
  else if (w == 1) { src = Al; ld = lda; }
  else if (w == 2) { src = Bh; ld = ldb; }
  else             { src = Bl; ld = ldb; }
  u16* myTile = lds + w * 4096;
  const int srow = ln >> 2;                     // row within 16-row group
  const int csw  = ((ln & 3) - (ln >> 3)) & 3;  // source logical chunk (swizzled)
  const int ml = ln & 15, quad = ln >> 4;
  const int fo2 = (((ln >> 4) + ((ln >> 1) & 3)) & 3) * 8;  // swizzled frag offset
  const int wr = (w >> 1) * 64, wc = (w & 1) * 64;

  for (int ks = 0; ks < KSTEPS; ++ks) {
    const int k0 = ks * 32;
    const u16* sb = src + (size_t)srow * ld + k0 + csw * 8;
#pragma unroll
    for (int t = 0; t < 8; ++t)
      gl2lds16(sb + (size_t)(t * 16) * ld, myTile + t * 512);
    __syncthreads();
    s8v ah[4], al[4], bh[4], bl[4];
#pragma unroll
    for (int i = 0; i < 4; ++i) {
      const int ra = (wr + i * 16 + ml) * 32 + fo2;
      ah[i] = *(const s8v*)&lds[ra];
      al[i] = *(const s8v*)&lds[4096 + ra];
      const int rb = (wc + i * 16 + ml) * 32 + fo2;
      bh[i] = *(const s8v*)&lds[8192 + rb];
      bl[i] = *(const s8v*)&lds[12288 + rb];
    }
#pragma unroll
    for (int i = 0; i < 4; ++i)
#pragma unroll
      for (int j = 0; j < 4; ++j)
        acc[i][j] = __builtin_amdgcn_mfma_f32_16x16x32_bf16(ah[i], bh[j], acc[i][j], 0, 0, 0);
#pragma unroll
    for (int i = 0; i < 4; ++i)
#pragma unroll
      for (int j = 0; j < 4; ++j)
        acc[i][j] = __builtin_amdgcn_mfma_f32_16x16x32_bf16(ah[i], bl[j], acc[i][j], 0, 0, 0);
#pragma unroll
    for (int i = 0; i < 4; ++i)
#pragma unroll
      for (int j = 0; j < 4; ++j)
        acc[i][j] = __builtin_amdgcn_mfma_f32_16x16x32_bf16(al[i], bh[j], acc[i][j], 0, 0, 0);
    __syncthreads();
  }
}

// ---- prep: split x into hi/lo bf16 ----
__global__ __launch_bounds__(256) void splitx(const float* __restrict__ x,
                                              u16* __restrict__ xh, u16* __restrict__ xl)
{
  const int i = blockIdx.x * 256 + threadIdx.x;       // per float4
  const float4 v = ((const float4*)x)[i];
  u16 h0 = f2bf(v.x), h1 = f2bf(v.y), h2 = f2bf(v.z), h3 = f2bf(v.w);
  ushort4 hv = make_ushort4(h0, h1, h2, h3);
  ushort4 lv = make_ushort4(f2bf(v.x - bf2f(h0)), f2bf(v.y - bf2f(h1)),
                            f2bf(v.z - bf2f(h2)), f2bf(v.w - bf2f(h3)));
  ((ushort4*)xh)[i] = hv;
  ((ushort4*)xl)[i] = lv;
}

// ---- prep: transpose + split weights: WT[z][n][k] = W_z[k][n] ----
__global__ __launch_bounds__(256) void wsplit(
    const float* __restrict__ Wq, const float* __restrict__ Wk,
    const float* __restrict__ Wv, const float* __restrict__ Wo,
    u16* __restrict__ WTh, u16* __restrict__ WTl)
{
  __shared__ float t[32][33];
  const int z = blockIdx.z;
  const float* W = (z == 0) ? Wq : (z == 1) ? Wk : (z == 2) ? Wv : Wo;
  const int n0 = blockIdx.x * 32, k0 = blockIdx.y * 32;
  const int tx = threadIdx.x & 31, ty = threadIdx.x >> 5;     // ty 0..7
#pragma unroll
  for (int i = 0; i < 4; ++i)
    t[ty + 8 * i][tx] = W[(size_t)(k0 + ty + 8 * i) * HID + n0 + tx];
  __syncthreads();
#pragma unroll
  for (int i = 0; i < 4; ++i) {
    const float v = t[tx][ty + 8 * i];                        // W[k0+tx][n0+ty+8i]
    const size_t idx = (size_t)z * HID * HID + (size_t)(n0 + ty + 8 * i) * HID + k0 + tx;
    const u16 hi = f2bf(v);
    WTh[idx] = hi;
    WTl[idx] = f2bf(v - bf2f(hi));
  }
}

// ---- QKV GEMM: z=0 -> q split, z=1 -> k split, z=2 -> v fp32 temp ----
__global__ __launch_bounds__(256) void qkv_mm(
    const u16* __restrict__ xh, const u16* __restrict__ xl,
    const u16* __restrict__ WTh, const u16* __restrict__ WTl,
    const float* __restrict__ bq, const float* __restrict__ bk, const float* __restrict__ bv,
    u16* __restrict__ qh, u16* __restrict__ ql,
    u16* __restrict__ kh, u16* __restrict__ kl, float* __restrict__ vtmp)
{
  __shared__ u16 lds[16384];
  const int z = blockIdx.z;
  const int bm = blockIdx.y * 128, bn = blockIdx.x * 128;
  const size_t wtoff = (size_t)z * HID * HID + (size_t)bn * HID;
  f4v acc[4][4];
#pragma unroll
  for (int i = 0; i < 4; ++i)
#pragma unroll
    for (int j = 0; j < 4; ++j) acc[i][j] = (f4v)0.f;
  mm_core128<24>(xh + (size_t)bm * HID, xl + (size_t)bm * HID, HID,
                 WTh + wtoff, WTl + wtoff, HID, lds, acc);
  const int tid = threadIdx.x, w = tid >> 6, ln = tid & 63;
  const int ml = ln & 15, quad = ln >> 4;
  const int wr = (w >> 1) * 64, wc = (w & 1) * 64;
  const float* bias = (z == 0) ? bq : (z == 1) ? bk : bv;
#pragma unroll
  for (int i = 0; i < 4; ++i)
#pragma unroll
    for (int j = 0; j < 4; ++j) {
      const int gcol = bn + wc + j * 16 + ml;
      const float bv_ = bias[gcol];
#pragma unroll
      for (int r = 0; r < 4; ++r) {
        const int grow = bm + wr + i * 16 + quad * 4 + r;
        const float v = acc[i][j][r] + bv_;
        const size_t idx = (size_t)grow * HID + gcol;
        if (z == 2) {
          vtmp[idx] = v;
        } else {
          const u16 hi = f2bf(v);
          const u16 lo = f2bf(v - bf2f(hi));
          if (z == 0) { qh[idx] = hi; ql[idx] = lo; }
          else        { kh[idx] = hi; kl[idx] = lo; }
        }
      }
    }
}

// ---- prep: transpose + split v: vT[b][n][c] = vtmp[b][c][n] ----
__global__ __launch_bounds__(256) void vtrans(const float* __restrict__ vtmp,
                                              u16* __restrict__ vTh, u16* __restrict__ vTl)
{
  __shared__ float t[32][33];
  const int b = blockIdx.z, n0 = blockIdx.x * 32, c0 = blockIdx.y * 32;
  const int tx = threadIdx.x & 31, ty = threadIdx.x >> 5;
  const float* src = vtmp + (size_t)b * SEQ * HID;
#pragma unroll
  for (int i = 0; i < 4; ++i)
    t[ty + 8 * i][tx] = src[(size_t)(c0 + ty + 8 * i) * HID + n0 + tx];
  __syncthreads();
#pragma unroll
  for (int i = 0; i < 4; ++i) {
    const float v = t[tx][ty + 8 * i];                        // v[c0+tx][n0+ty+8i]
    const size_t idx = (size_t)b * HID * SEQ + (size_t)(n0 + ty + 8 * i) * SEQ + c0 + tx;
    const u16 hi = f2bf(v);
    vTh[idx] = hi;
    vTl[idx] = f2bf(v - bf2f(hi));
  }
}

// ---- scores GEMM + fused rel-bias/scale/dist-mask epilogue (fp32 out) ----
__global__ __launch_bounds__(256) void scores_mm(
    const u16* __restrict__ qh, const u16* __restrict__ ql,
    const u16* __restrict__ kh, const u16* __restrict__ kl, float* __restrict__ sc)
{
  __shared__ u16 lds[16384];
  const int z = blockIdx.z, b = z >> 2, hh = z & 3;
  const int bm = blockIdx.y * 128, bn = blockIdx.x * 128;
  const size_t abase = (size_t)(b * SEQ + bm) * HID + hh * 192;
  const size_t bbase = (size_t)(b * SEQ + bn) * HID + hh * 192;
  f4v acc[4][4];
#pragma unroll
  for (int i = 0; i < 4; ++i)
#pragma unroll
    for (int j = 0; j < 4; ++j) acc[i][j] = (f4v)0.f;
  mm_core128<6>(qh + abase, ql + abase, HID, kh + bbase, kl + bbase, HID, lds, acc);
  const int tid = threadIdx.x, w = tid >> 6, ln = tid & 63;
  const int ml = ln & 15, quad = ln >> 4;
  const int wr = (w >> 1) * 64, wc = (w & 1) * 64;
  float* sch = sc + (size_t)z * SEQ * SEQ;
#pragma unroll
  for (int i = 0; i < 4; ++i)
#pragma unroll
    for (int j = 0; j < 4; ++j) {
      const int scol = bn + wc + j * 16 + ml;
#pragma unroll
      for (int r = 0; r < 4; ++r) {
        const int srow = bm + wr + i * 16 + quad * 4 + r;
        const float dist = fabsf((float)(srow - scol));
        const float rel = __expf(-0.1f * fminf(dist, 5.0f));
        sch[(size_t)srow * SEQ + scol] =
            (acc[i][j][r] + rel) * INV_SQRT_D - 0.1f * dist;
      }
    }
}

// ---- softmax in-place, writes probs hi/lo bf16 into the same row bytes ----
__global__ __launch_bounds__(256) void softmax_split(float* __restrict__ sc)
{
  const int blk = blockIdx.x;                  // 0..8191
  const int z = blk >> 7, rg = blk & 127;
  const int tid = threadIdx.x;
  const int rr = tid >> 6, lane = tid & 63;
  const int r = rg * 4 + rr;
  float* row = sc + (size_t)z * SEQ * SEQ + (size_t)r * SEQ;
  float4 v0 = *(const float4*)(row + lane * 8);
  float4 v1 = *(const float4*)(row + lane * 8 + 4);
  float mx = fmaxf(fmaxf(fmaxf(v0.x, v0.y), fmaxf(v0.z, v0.w)),
                   fmaxf(fmaxf(v1.x, v1.y), fmaxf(v1.z, v1.w)));
#pragma unroll
  for (int o = 32; o > 0; o >>= 1) mx = fmaxf(mx, __shfl_xor(mx, o, 64));
  v0.x = __expf(v0.x - mx); v0.y = __expf(v0.y - mx);
  v0.z = __expf(v0.z - mx); v0.w = __expf(v0.w - mx);
  v1.x = __expf(v1.x - mx); v1.y = __expf(v1.y - mx);
  v1.z = __expf(v1.z - mx); v1.w = __expf(v1.w - mx);
  float s = v0.x + v0.y + v0.z + v0.w + v1.x + v1.y + v1.z + v1.w;
#pragma unroll
  for (int o = 32; o > 0; o >>= 1) s += __shfl_xor(s, o, 64);
  const float inv = 1.0f / s;
  float p[8] = {v0.x * inv, v0.y * inv, v0.z * inv, v0.w * inv,
                v1.x * inv, v1.y * inv, v1.z * inv, v1.w * inv};
  u16 hi[8], lo[8];
#pragma unroll
  for (int t = 0; t < 8; ++t) {
    hi[t] = f2bf(p[t]);
    lo[t] = f2bf(p[t] - bf2f(hi[t]));
  }
  u16* ph = (u16*)row;                          // [0,512) hi, [512,1024) lo
  ushort4* d0 = (ushort4*)&ph[lane * 8];
  d0[0] = make_ushort4(hi[0], hi[1], hi[2], hi[3]);
  d0[1] = make_ushort4(hi[4], hi[5], hi[6], hi[7]);
  ushort4* d1 = (ushort4*)&ph[512 + lane * 8];
  d1[0] = make_ushort4(lo[0], lo[1], lo[2], lo[3]);
  d1[1] = make_ushort4(lo[4], lo[5], lo[6], lo[7]);
}

// ---- PV GEMM: 64x192 tile, probs(split) @ vT(split) -> ctx split ----
__global__ __launch_bounds__(256) void pv_mm(
    const u16* __restrict__ pbase, const u16* __restrict__ vTh, const u16* __restrict__ vTl,
    u16* __restrict__ ch, u16* __restrict__ cl)
{
  __shared__ u16 lds[16384];   // Ah@0(2048) Al@2048 Bh@4096(6144) Bl@10240(6144)
  const int z = blockIdx.y, b = z >> 2, hh = z & 3;
  const int bm = blockIdx.x * 64;
  const u16* ah_g = pbase + (size_t)z * SEQ * 1024 + (size_t)bm * 1024;  // ld 1024
  const u16* al_g = ah_g + 512;
  const u16* bh_g = vTh + (size_t)b * HID * SEQ + (size_t)(hh * 192) * SEQ;  // ld 512
  const u16* bl_g = vTl + (size_t)b * HID * SEQ + (size_t)(hh * 192) * SEQ;
  const int tid = threadIdx.x, w = tid >> 6, ln = tid & 63;
  const int srow = ln >> 2;
  const int csw  = ((ln & 3) - (ln >> 3)) & 3;  // swizzled source chunk
  const int schunk = csw * 8;
  const int ml = ln & 15, quad = ln >> 4;
  const int fo2 = (((ln >> 4) + ((ln >> 1) & 3)) & 3) * 8;
  f4v acc[12];
#pragma unroll
  for (int j = 0; j < 12; ++j) acc[j] = (f4v)0.f;

  for (int ks = 0; ks < 16; ++ks) {
    const int k0 = ks * 32;
#pragma unroll
    for (int s = 0; s < 8; ++s) {
      const int p = w * 8 + s;
      const u16* g; u16* l;
      if (p < 4)       { g = ah_g + (size_t)(p * 16 + srow) * 1024 + k0 + schunk; l = lds + p * 512; }
      else if (p < 8)  { const int t = p - 4;  g = al_g + (size_t)(t * 16 + srow) * 1024 + k0 + schunk; l = lds + 2048 + t * 512; }
      else if (p < 20) { const int t = p - 8;  g = bh_g + (size_t)(t * 16 + srow) * 512 + k0 + schunk; l = lds + 4096 + t * 512; }
      else             { const int t = p - 20; g = bl_g + (size_t)(t * 16 + srow) * 512 + k0 + schunk; l = lds + 10240 + t * 512; }
      gl2lds16(g, l);
    }
    __syncthreads();
    const int ra = (w * 16 + ml) * 32 + fo2;
    const s8v a_h = *(const s8v*)&lds[ra];
    const s8v a_l = *(const s8v*)&lds[2048 + ra];
    s8v bh[12], bl[12];
#pragma unroll
    for (int j = 0; j < 12; ++j) {
      const int rb = (j * 16 + ml) * 32 + fo2;
      bh[j] = *(const s8v*)&lds[4096 + rb];
      bl[j] = *(const s8v*)&lds[10240 + rb];
    }
#pragma unroll
    for (int j = 0; j < 12; ++j)
      acc[j] = __builtin_amdgcn_mfma_f32_16x16x32_bf16(a_h, bh[j], acc[j], 0, 0, 0);
#pragma unroll
    for (int j = 0; j < 12; ++j)
      acc[j] = __builtin_amdgcn_mfma_f32_16x16x32_bf16(a_h, bl[j], acc[j], 0, 0, 0);
#pragma unroll
    for (int j = 0; j < 12; ++j)
      acc[j] = __builtin_amdgcn_mfma_f32_16x16x32_bf16(a_l, bh[j], acc[j], 0, 0, 0);
    __syncthreads();
  }
#pragma unroll
  for (int j = 0; j < 12; ++j) {
    const int gcol = hh * 192 + j * 16 + ml;
#pragma unroll
    for (int r = 0; r < 4; ++r) {
      const int m = bm + w * 16 + quad * 4 + r;
      const float v = acc[j][r];
      const size_t idx = (size_t)(b * SEQ + m) * HID + gcol;
      const u16 hi = f2bf(v);
      ch[idx] = hi;
      cl[idx] = f2bf(v - bf2f(hi));
    }
  }
}

// ---- projection GEMM + bias + residual -> h fp32 ----
__global__ __launch_bounds__(256) void proj_mm(
    const u16* __restrict__ ch, const u16* __restrict__ cl,
    const u16* __restrict__ WTh, const u16* __restrict__ WTl,
    const float* __restrict__ bo, const float* __restrict__ x, float* __restrict__ h)
{
  __shared__ u16 lds[16384];
  const int bm = blockIdx.y * 128, bn = blockIdx.x * 128;
  const size_t wtoff = (size_t)3 * HID * HID + (size_t)bn * HID;
  f4v acc[4][4];
#pragma unroll
  for (int i = 0; i < 4; ++i)
#pragma unroll
    for (int j = 0; j < 4; ++j) acc[i][j] = (f4v)0.f;
  mm_core128<24>(ch + (size_t)bm * HID, cl + (size_t)bm * HID, HID,
                 WTh + wtoff, WTl + wtoff, HID, lds, acc);
  const int tid = threadIdx.x, w = tid >> 6, ln = tid & 63;
  const int ml = ln & 15, quad = ln >> 4;
  const int wr = (w >> 1) * 64, wc = (w & 1) * 64;
#pragma unroll
  for (int i = 0; i < 4; ++i)
#pragma unroll
    for (int j = 0; j < 4; ++j) {
      const int gcol = bn + wc + j * 16 + ml;
      const float bv_ = bo[gcol];
#pragma unroll
      for (int r = 0; r < 4; ++r) {
        const int grow = bm + wr + i * 16 + quad * 4 + r;
        const size_t idx = (size_t)grow * HID + gcol;
        h[idx] = acc[i][j][r] + bv_ + x[idx];
      }
    }
}

// ---- LayerNorm + 9-label classifier ----
__global__ __launch_bounds__(256) void ln_logits_kernel(
    const float* __restrict__ h, const float* __restrict__ g,
    const float* __restrict__ bta, const float* __restrict__ Ws,
    const float* __restrict__ bsv, float* __restrict__ span)
{
  const int row = blockIdx.x;
  const int tid = threadIdx.x;
  const float* hr = h + (size_t)row * HID;
  const float x0 = hr[tid], x1 = hr[tid + 256], x2 = hr[tid + 512];
  float s = x0 + x1 + x2;
  float sq = x0 * x0 + x1 * x1 + x2 * x2;
#pragma unroll
  for (int o = 32; o > 0; o >>= 1) { s += __shfl_down(s, o, 64); sq += __shfl_down(sq, o, 64); }
  __shared__ float red[8];
  __shared__ float smu, srs;
  const int wid = tid >> 6, lid = tid & 63;
  if (lid == 0) { red[wid] = s; red[4 + wid] = sq; }
  __syncthreads();
  if (tid == 0) {
    const float ts = red[0] + red[1] + red[2] + red[3];
    const float tq = red[4] + red[5] + red[6] + red[7];
    const float mu = ts / 768.0f;
    const float var = tq / 768.0f - mu * mu;
    smu = mu; srs = rsqrtf(var + 1e-5f);
  }
  __syncthreads();
  const float mu = smu, rs = srs;
  const float n0 = (x0 - mu) * rs * g[tid] + bta[tid];
  const float n1 = (x1 - mu) * rs * g[tid + 256] + bta[tid + 256];
  const float n2 = (x2 - mu) * rs * g[tid + 512] + bta[tid + 512];
  float pl[9];
#pragma unroll
  for (int l = 0; l < 9; ++l)
    pl[l] = n0 * Ws[(size_t)tid * 9 + l]
          + n1 * Ws[(size_t)(tid + 256) * 9 + l]
          + n2 * Ws[(size_t)(tid + 512) * 9 + l];
#pragma unroll
  for (int l = 0; l < 9; ++l)
#pragma unroll
    for (int o = 32; o > 0; o >>= 1) pl[l] += __shfl_down(pl[l], o, 64);
  __shared__ float lred[4][9];
  if (lid == 0) {
#pragma unroll
    for (int l = 0; l < 9; ++l) lred[wid][l] = pl[l];
  }
  __syncthreads();
  if (tid < 9) {
    span[(size_t)row * 9 + tid] =
        lred[0][tid] + lred[1][tid] + lred[2][tid] + lred[3][tid] + bsv[tid];
  }
}

// ---- entity-bias bump ----
__global__ __launch_bounds__(256) void bump_kernel(
    const float* __restrict__ span, const float* __restrict__ eb, float* __restrict__ out)
{
  const int idx = blockIdx.x * 256 + threadIdx.x;
  if (idx >= ROWS) return;
  const int j = idx & (SEQ - 1);
  const float* sl = span + (size_t)idx * 9;
  float v[9];
#pragma unroll
  for (int l = 0; l < 9; ++l) v[l] = sl[l];
  if (j >= 1) {
    const float* sp = sl - 9;
    float m = sp[0]; int am = 0;
#pragma unroll
    for (int l = 1; l < 9; ++l) { const float t = sp[l]; if (t > m) { m = t; am = l; } }
    if (am == 1) v[2] += 2.0f * eb[2];
  }
#pragma unroll
  for (int l = 0; l < 9; ++l) out[(size_t)idx * 9 + l] = v[l];
}

extern "C" void kernel_launch(void* const* d_in, const int* in_sizes, int n_in,
                              void* d_out, int out_size, void* d_ws, size_t ws_size,
                              hipStream_t stream)
{
  (void)in_sizes; (void)n_in; (void)out_size; (void)ws_size;
  const float* x   = (const float*)d_in[0];
  const float* Wq  = (const float*)d_in[1];
  const float* bq  = (const float*)d_in[2];
  const float* Wk  = (const float*)d_in[3];
  const float* bk  = (const float*)d_in[4];
  const float* Wv  = (const float*)d_in[5];
  const float* bv  = (const float*)d_in[6];
  const float* Wo  = (const float*)d_in[7];
  const float* bo  = (const float*)d_in[8];
  const float* lng = (const float*)d_in[9];
  const float* lnb = (const float*)d_in[10];
  const float* Ws  = (const float*)d_in[11];
  const float* bs  = (const float*)d_in[12];
  const float* eb  = (const float*)d_in[13];
  float* out = (float*)d_out;

  char* ws = (char*)d_ws;
  // byte offsets (all 256-aligned); total 152,338,432 B
  u16* xh  = (u16*)(ws + 0);                       // 12,582,912
  u16* xl  = (u16*)(ws + 12582912);                // 12,582,912
  u16* vTh = xh;                                   // reuse x region after qkv
  u16* vTl = xl;
  u16* WTh = (u16*)(ws + 25165824);                // 4,718,592
  u16* WTl = (u16*)(ws + 29884416);                // 4,718,592
  u16* qh  = (u16*)(ws + 34603008);                // 12,582,912
  u16* ql  = (u16*)(ws + 47185920);
  u16* kh  = (u16*)(ws + 59768832);
  u16* kl  = (u16*)(ws + 72351744);
  float* scb = (float*)(ws + 84934656);            // 67,108,864 (also vtmp, then h)
  float* spanb = (float*)(ws + 152043520);         // 294,912
  float* vtmp = scb;
  float* hb = scb;
  u16* ctxh = qh;                                  // q dead after scores
  u16* ctxl = ql;

  splitx<<<dim3(1572864 / 256), 256, 0, stream>>>(x, xh, xl);
  wsplit<<<dim3(24, 24, 4), 256, 0, stream>>>(Wq, Wk, Wv, Wo, WTh, WTl);
  qkv_mm<<<dim3(6, 64, 3), 256, 0, stream>>>(xh, xl, WTh, WTl, bq, bk, bv,
                                             qh, ql, kh, kl, vtmp);
  vtrans<<<dim3(24, 16, 16), 256, 0, stream>>>(vtmp, vTh, vTl);
  scores_mm<<<dim3(4, 4, 64), 256, 0, stream>>>(qh, ql, kh, kl, scb);
  softmax_split<<<dim3(8192), 256, 0, stream>>>(scb);
  pv_mm<<<dim3(8, 64), 256, 0, stream>>>((const u16*)scb, vTh, vTl, ctxh, ctxl);
  proj_mm<<<dim3(6, 64), 256, 0, stream>>>(ctxh, ctxl, WTh, WTl, bo, x, hb);
  ln_logits_kernel<<<dim3(ROWS), 256, 0, stream>>>(hb, lng, lnb, Ws, bs, spanb);
  bump_kernel<<<dim3(ROWS / 256), 256, 0, stream>>>(spanb, eb, out);
}